// Round 1
// baseline (888.777 us; speedup 1.0000x reference)
//
#include <hip/hip_runtime.h>
#include <math.h>

// Problem constants: B=8, C=512, NH=4, H=W=64, CH=64, HC=16, P=H*W=4096

// ---------------------------------------------------------------- pos tables
__global__ __launch_bounds__(64) void pos_kernel(float* __restrict__ PH,
                                                 float* __restrict__ PW) {
    const float r = 0.03597789207798663f; // ln(10000)/256
    int c = blockIdx.x;   // [0,512)
    int t = threadIdx.x;  // [0,64)  (h for PH, w for PW)
    // PH(c,h): raw reshape of (h=64, c=512) sin/cos table to (c,h)
    int i = c >> 3;
    int j = ((c & 7) << 6) | t;
    float ph;
    if (j < 256) ph = sinf((float)i * expf(-(float)j * r));
    else         ph = cosf((float)i * expf(-(float)(j - 256) * r));
    PH[c * 64 + t] = ph;
    // PW(c,w): raw reshape of (256, 128) sin|cos table to (c,w)
    int tt = c >> 1;
    float dv = expf(-(float)tt * r);
    PW[c * 64 + t] = (c & 1) ? cosf((float)t * dv) : sinf((float)t * dv);
}

// ---------------------------------------------------------------- qkv conv1x1
// q/k/v[b, m(=n*16+hc), p] = sum_c W[m][c] * (x[b,c,p] + PH[c,h] + PW[c,w]) + bias
__global__ __launch_bounds__(256) void qkv_kernel(
    const float* __restrict__ x,
    const float* __restrict__ wq, const float* __restrict__ bq,
    const float* __restrict__ wk, const float* __restrict__ bk,
    const float* __restrict__ wv, const float* __restrict__ bv,
    const float* __restrict__ PH, const float* __restrict__ PW,
    float* __restrict__ q, float* __restrict__ k, float* __restrict__ v) {
    __shared__ float xt[64][65];
    int b  = blockIdx.y;
    int pt = blockIdx.x;          // h row index; pixels p = pt*64 + [0,64)
    int tid = threadIdx.x;
    int ty = __builtin_amdgcn_readfirstlane(tid >> 6); // wave id 0..3
    int tx = tid & 63;
    float accq[16], acck[16], accv[16];
#pragma unroll
    for (int i = 0; i < 16; i++) {
        int m = ty * 16 + i;
        accq[i] = bq[m]; acck[i] = bk[m]; accv[i] = bv[m];
    }
    for (int kc = 0; kc < 512; kc += 64) {
        __syncthreads();
#pragma unroll
        for (int it = 0; it < 16; it++) {
            int idx = tid + it * 256;
            int cl = idx >> 6, pl = idx & 63;
            int c = kc + cl;
            xt[cl][pl] = x[(b * 512 + c) * 4096 + pt * 64 + pl]
                       + PH[c * 64 + pt] + PW[c * 64 + pl];
        }
        __syncthreads();
        for (int cl = 0; cl < 64; cl++) {
            float xv = xt[cl][tx];
            int c = kc + cl;
#pragma unroll
            for (int i = 0; i < 16; i++) {
                int m = ty * 16 + i;
                accq[i] = fmaf(wq[m * 512 + c], xv, accq[i]);
                acck[i] = fmaf(wk[m * 512 + c], xv, acck[i]);
                accv[i] = fmaf(wv[m * 512 + c], xv, accv[i]);
            }
        }
    }
#pragma unroll
    for (int i = 0; i < 16; i++) {
        int m = ty * 16 + i;
        int o = (b * 64 + m) * 4096 + pt * 64 + tx;
        q[o] = accq[i]; k[o] = acck[i]; v[o] = accv[i];
    }
}

// ---------------------------------------------------------------- fused attention
// Block (b, a, n): conc rows [b,a,n,d,0:128], softmax, then BOTH consumers:
//   H-half -> out_H for (b, n, w=a);  W-half -> out_W for (b, nv=a>>4, hv=(a&15)*4+n)
// Scatter (faithful to the torch reshape bugs) with atomicAdd into outsum.
__global__ __launch_bounds__(256) void attn_kernel(
    const float* __restrict__ q, const float* __restrict__ k,
    const float* __restrict__ v, float* __restrict__ outsum) {
    __shared__ float QH[16][64], KH[16][64], QW[16][64], KW[16][64],
                     VH[16][64], VW[16][64];
    __shared__ float E[64][129];
    int a = blockIdx.x, n = blockIdx.y, b = blockIdx.z;
    int tid = threadIdx.x;
    int nv = a >> 4;
    int hv = ((a & 15) << 2) | n;
    const float* qb  = q + (b * 64 + n * 16) * 4096;
    const float* kb  = k + (b * 64 + n * 16) * 4096;
    const float* vb  = v + (b * 64 + n * 16) * 4096;
    const float* vwb = v + (b * 64 + nv * 16) * 4096 + hv * 64;
#pragma unroll
    for (int it = 0; it < 4; it++) {
        int idx = tid + it * 256;
        int hc = idx >> 6, d = idx & 63;
        QH[hc][d] = qb[hc * 4096 + d * 64 + a];   // q[b,n,hc,d,a]
        KH[hc][d] = kb[hc * 4096 + d * 64 + a];   // k[b,n,hc,d,a]
        VH[hc][d] = vb[hc * 4096 + d * 64 + a];   // v[b,n,hc,d,a]
        QW[hc][d] = qb[hc * 4096 + a * 64 + d];   // q[b,n,hc,a,d]
        KW[hc][d] = kb[hc * 4096 + a * 64 + d];   // k[b,n,hc,a,d]
        VW[hc][d] = vwb[hc * 4096 + d];           // v[b,nv,hc,hv,d]
    }
    __syncthreads();
    // energies: 64 d x 128 j ; branch is wave-uniform (j-range fixed per wave)
    int j = tid & 127;
    int dh = tid >> 7;
    if (j < 64) {
        for (int it = 0; it < 32; it++) {
            int d = dh + it * 2;
            float e = 0.f;
#pragma unroll
            for (int hc = 0; hc < 16; hc++) e = fmaf(QH[hc][d], KH[hc][j], e);
            E[d][j] = (j == d) ? -INFINITY : e;
        }
    } else {
        int jj = j - 64;
        for (int it = 0; it < 32; it++) {
            int d = dh + it * 2;
            float e = 0.f;
#pragma unroll
            for (int hc = 0; hc < 16; hc++) e = fmaf(QW[hc][d], KW[hc][jj], e);
            E[d][j] = e;
        }
    }
    __syncthreads();
    // row softmax over 128 mixed logits
    if (tid < 64) {
        int d = tid;
        float mx = -INFINITY;
        for (int j2 = 0; j2 < 128; j2++) mx = fmaxf(mx, E[d][j2]);
        float l = 0.f;
        for (int j2 = 0; j2 < 128; j2++) l += expf(E[d][j2] - mx);
        float inv = 1.0f / l;
        for (int j2 = 0; j2 < 128; j2++) E[d][j2] = expf(E[d][j2] - mx) * inv;
    }
    __syncthreads();
    // PV for both halves + scatter into final (b, c', h', w') layout
#pragma unroll
    for (int t2 = 0; t2 < 4; t2++) {
        int idx = tid + t2 * 256;
        int hc = idx >> 6, dd = idx & 63;
        float oh = 0.f, ow = 0.f;
        for (int j2 = 0; j2 < 64; j2++) {
            oh = fmaf(VH[hc][j2], E[dd][j2],      oh);
            ow = fmaf(VW[hc][j2], E[dd][64 + j2], ow);
        }
        // out_H final: c'=hc*4+(dd>>4), h'=(dd&15)*4+n, w'=a
        atomicAdd(&outsum[(b * 64 + hc * 4 + (dd >> 4)) * 4096
                          + ((((dd & 15) << 2) | n) << 6) + a], oh);
        // out_W final: c'=hc*4+nv, h'=dd, w'=hv
        atomicAdd(&outsum[(b * 64 + hc * 4 + nv) * 4096 + (dd << 6) + hv], ow);
    }
}

// ---------------------------------------------------------------- final conv + residual
__global__ __launch_bounds__(256) void final_kernel(
    const float* __restrict__ outsum, const float* __restrict__ wo,
    const float* __restrict__ bo, const float* __restrict__ gamma,
    const float* __restrict__ x, const float* __restrict__ PH,
    const float* __restrict__ PW, float* __restrict__ out) {
    __shared__ float st[64][65];
    int pt = blockIdx.x, mc = blockIdx.y, b = blockIdx.z;
    int tid = threadIdx.x;
#pragma unroll
    for (int it = 0; it < 16; it++) {
        int idx = tid + it * 256;
        int cl = idx >> 6, pl = idx & 63;
        st[cl][pl] = outsum[(b * 64 + cl) * 4096 + pt * 64 + pl];
    }
    __syncthreads();
    int ty = __builtin_amdgcn_readfirstlane(tid >> 6);
    int tx = tid & 63;
    float g = gamma[0];
    for (int i = 0; i < 32; i++) {
        int m = mc * 128 + ty * 32 + i;
        float acc = bo[m];
#pragma unroll
        for (int cl = 0; cl < 64; cl++)
            acc = fmaf(wo[m * 64 + cl], st[cl][tx], acc);
        int o = (b * 512 + m) * 4096 + pt * 64 + tx;
        out[o] = g * acc + x[o] + PH[m * 64 + pt] + PW[m * 64 + tx];
    }
}

// ---------------------------------------------------------------- launch
extern "C" void kernel_launch(void* const* d_in, const int* in_sizes, int n_in,
                              void* d_out, int out_size, void* d_ws, size_t ws_size,
                              hipStream_t stream) {
    const float* x     = (const float*)d_in[0];
    const float* wq    = (const float*)d_in[1];
    const float* bq    = (const float*)d_in[2];
    const float* wk    = (const float*)d_in[3];
    const float* bk    = (const float*)d_in[4];
    const float* wv    = (const float*)d_in[5];
    const float* bv    = (const float*)d_in[6];
    const float* wo    = (const float*)d_in[7];
    const float* bo    = (const float*)d_in[8];
    const float* gamma = (const float*)d_in[9];
    float* out = (float*)d_out;
    float* ws  = (float*)d_ws;

    float* PH = ws;                       // 512*64
    float* PW = PH + 512 * 64;            // 512*64
    float* q  = PW + 512 * 64;            // 8*64*4096
    float* k  = q + 8 * 64 * 4096;
    float* v  = k + 8 * 64 * 4096;
    float* outsum = v + 8 * 64 * 4096;    // 8*64*4096
    // total ws: ~33.8 MB

    pos_kernel<<<dim3(512), dim3(64), 0, stream>>>(PH, PW);
    qkv_kernel<<<dim3(64, 8), dim3(256), 0, stream>>>(x, wq, bq, wk, bk, wv, bv,
                                                      PH, PW, q, k, v);
    hipMemsetAsync(outsum, 0, (size_t)8 * 64 * 4096 * sizeof(float), stream);
    attn_kernel<<<dim3(64, 4, 8), dim3(256), 0, stream>>>(q, k, v, outsum);
    final_kernel<<<dim3(64, 4, 8), dim3(256), 0, stream>>>(outsum, wo, bo, gamma,
                                                           x, PH, PW, out);
}

// Round 2
// 555.705 us; speedup vs baseline: 1.5994x; 1.5994x over previous
//
#include <hip/hip_runtime.h>
#include <math.h>

// Problem constants: B=8, C=512, NH=4, H=W=64, CH=64, HC=16, P=H*W=4096

typedef unsigned int u32;
typedef unsigned short u16;
typedef __attribute__((ext_vector_type(8))) short short8;  // 8 bf16 = 4 VGPRs
typedef __attribute__((ext_vector_type(4))) float f32x4;

__device__ __forceinline__ u16 f2bf(float v) {
    u32 u = __float_as_uint(v);
    u32 r = (u + 0x7FFFu + ((u >> 16) & 1u)) >> 16;
    return (u16)r;
}

__device__ __forceinline__ void gll16(const void* g, void* l) {
    __builtin_amdgcn_global_load_lds(
        (const __attribute__((address_space(1))) u32*)g,
        (__attribute__((address_space(3))) u32*)l, 16, 0, 0);
}

// ---------------------------------------------------------------- pos tables
__global__ __launch_bounds__(64) void pos_kernel(float* __restrict__ PH,
                                                 float* __restrict__ PW) {
    const float r = 0.03597789207798663f; // ln(10000)/256
    int c = blockIdx.x;   // [0,512)
    int t = threadIdx.x;  // [0,64)
    int i = c >> 3;
    int j = ((c & 7) << 6) | t;
    float ph;
    if (j < 256) ph = sinf((float)i * expf(-(float)j * r));
    else         ph = cosf((float)i * expf(-(float)(j - 256) * r));
    PH[c * 64 + t] = ph;
    int tt = c >> 1;
    float dv = expf(-(float)tt * r);
    PW[c * 64 + t] = (c & 1) ? cosf((float)t * dv) : sinf((float)t * dv);
}

// ---------------------------------------------------------------- weights -> bf16
// WT[192][512]: rows 0..63 = wq, 64..127 = wk, 128..191 = wv  (c contiguous)
__global__ __launch_bounds__(256) void wconv_kernel(
    const float* __restrict__ wq, const float* __restrict__ wk,
    const float* __restrict__ wv, u16* __restrict__ WT) {
    int i = blockIdx.x * 256 + threadIdx.x;   // [0, 98304)
    float v;
    if (i < 32768)      v = wq[i];
    else if (i < 65536) v = wk[i - 32768];
    else                v = wv[i - 65536];
    WT[i] = f2bf(v);
}

// ---------------------------------------------------------------- x+pos -> XT bf16 [b][p][c]
__global__ __launch_bounds__(256) void xpose_kernel(
    const float* __restrict__ x, const float* __restrict__ PH,
    const float* __restrict__ PW, u16* __restrict__ XT) {
    __shared__ u16 T[64 * 68];        // row stride 68 elems (136 B) -> 2-way max
    int ct = blockIdx.x;  // c tile [0,8)
    int pt = blockIdx.y;  // h row  [0,64)
    int b  = blockIdx.z;
    int tid = threadIdx.x;
    int c0 = ct * 64;
    const size_t xb = ((size_t)b * 512 + c0) * 4096 + pt * 64;
#pragma unroll
    for (int it = 0; it < 16; ++it) {
        int idx = tid + it * 256;
        int cl = idx >> 6, pl = idx & 63;
        float v = x[xb + (size_t)cl * 4096 + pl]
                + PH[(c0 + cl) * 64 + pt] + PW[(c0 + cl) * 64 + pl];
        T[pl * 68 + cl] = f2bf(v);    // transpose in LDS
    }
    __syncthreads();
#pragma unroll
    for (int jt = 0; jt < 4; ++jt) {
        int row = jt * 16 + (tid >> 4);   // p within tile
        int cq  = tid & 15;               // 4-c group
        ushort4 val = *(const ushort4*)&T[row * 68 + cq * 4];
        *(ushort4*)&XT[((size_t)b * 4096 + pt * 64 + row) * 512 + c0 + cq * 4] = val;
    }
}

// ---------------------------------------------------------------- qkv GEMM via MFMA
// C[m,p] = sum_c WT[mg*64+m][c] * XT[b][p][c] + bias ; tile 64m x 256p, BK=64
__global__ __launch_bounds__(256) void qkvm_kernel(
    const u16* __restrict__ XT, const u16* __restrict__ WT,
    const float* __restrict__ bq, const float* __restrict__ bk,
    const float* __restrict__ bv,
    float* __restrict__ q, float* __restrict__ k, float* __restrict__ v) {
    __shared__ u16 Ab[64 * 64];    //  8 KB  [m][c]
    __shared__ u16 Bb[256 * 64];   // 32 KB  [p][c]
    int pt = blockIdx.x;   // [0,16)
    int mg = blockIdx.y;   // [0,3)  q/k/v
    int b  = blockIdx.z;
    int tid  = threadIdx.x;
    int w    = tid >> 6;
    int lane = tid & 63;
    int ln15 = lane & 15, quad = lane >> 4;
    int p0 = pt * 256;
    const u16* Wg = WT + mg * 64 * 512;
    const u16* Xg = XT + ((size_t)b * 4096 + p0) * 512;

    f32x4 acc[4][4];
#pragma unroll
    for (int mf = 0; mf < 4; ++mf)
#pragma unroll
        for (int pf = 0; pf < 4; ++pf)
            acc[mf][pf] = (f32x4){0.f, 0.f, 0.f, 0.f};

    for (int kc = 0; kc < 512; kc += 64) {
        __syncthreads();
#pragma unroll
        for (int it = 0; it < 2; ++it) {         // stage A: 8 KB
            int idx = tid + it * 256;
            int r = idx >> 3, s = idx & 7;
            gll16(Wg + r * 512 + kc + s * 8, &Ab[idx * 8]);
        }
#pragma unroll
        for (int it = 0; it < 8; ++it) {         // stage B: 32 KB
            int idx = tid + it * 256;
            int r = idx >> 3, s = idx & 7;
            gll16(Xg + (size_t)r * 512 + kc + s * 8, &Bb[idx * 8]);
        }
        __syncthreads();
#pragma unroll
        for (int ks = 0; ks < 2; ++ks) {
            short8 af[4], bf[4];
#pragma unroll
            for (int mf = 0; mf < 4; ++mf)
                af[mf] = *(const short8*)&Ab[(mf * 16 + ln15) * 64 + ks * 32 + quad * 8];
#pragma unroll
            for (int pf = 0; pf < 4; ++pf)
                bf[pf] = *(const short8*)&Bb[(w * 64 + pf * 16 + ln15) * 64 + ks * 32 + quad * 8];
#pragma unroll
            for (int mf = 0; mf < 4; ++mf)
#pragma unroll
                for (int pf = 0; pf < 4; ++pf)
                    acc[mf][pf] = __builtin_amdgcn_mfma_f32_16x16x32_bf16(
                        af[mf], bf[pf], acc[mf][pf], 0, 0, 0);
        }
    }

    const float* bias = (mg == 0) ? bq : (mg == 1) ? bk : bv;
    float* outp       = (mg == 0) ? q  : (mg == 1) ? k  : v;
#pragma unroll
    for (int mf = 0; mf < 4; ++mf)
#pragma unroll
        for (int pf = 0; pf < 4; ++pf) {
            int p = p0 + w * 64 + pf * 16 + ln15;
#pragma unroll
            for (int reg = 0; reg < 4; ++reg) {
                int m = mf * 16 + quad * 4 + reg;
                outp[((size_t)b * 64 + m) * 4096 + p] = acc[mf][pf][reg] + bias[m];
            }
        }
}

// ---------------------------------------------------------------- fused attention
__global__ __launch_bounds__(256) void attn_kernel(
    const float* __restrict__ q, const float* __restrict__ k,
    const float* __restrict__ v, float* __restrict__ outsum) {
    __shared__ float QH[16][64], KH[16][64], QW[16][64], KW[16][64],
                     VH[16][64], VW[16][64];
    __shared__ float E[64][129];
    int a = blockIdx.x, n = blockIdx.y, b = blockIdx.z;
    int tid = threadIdx.x;
    int nv = a >> 4;
    int hv = ((a & 15) << 2) | n;
    const float* qb  = q + (b * 64 + n * 16) * 4096;
    const float* kb  = k + (b * 64 + n * 16) * 4096;
    const float* vb  = v + (b * 64 + n * 16) * 4096;
    const float* vwb = v + (b * 64 + nv * 16) * 4096 + hv * 64;
#pragma unroll
    for (int it = 0; it < 4; it++) {
        int idx = tid + it * 256;
        int hc = idx >> 6, d = idx & 63;
        QH[hc][d] = qb[hc * 4096 + d * 64 + a];
        KH[hc][d] = kb[hc * 4096 + d * 64 + a];
        VH[hc][d] = vb[hc * 4096 + d * 64 + a];
        QW[hc][d] = qb[hc * 4096 + a * 64 + d];
        KW[hc][d] = kb[hc * 4096 + a * 64 + d];
        VW[hc][d] = vwb[hc * 4096 + d];
    }
    __syncthreads();
    int j = tid & 127;
    int dh = tid >> 7;
    if (j < 64) {
        for (int it = 0; it < 32; it++) {
            int d = dh + it * 2;
            float e = 0.f;
#pragma unroll
            for (int hc = 0; hc < 16; hc++) e = fmaf(QH[hc][d], KH[hc][j], e);
            E[d][j] = (j == d) ? -INFINITY : e;
        }
    } else {
        int jj = j - 64;
        for (int it = 0; it < 32; it++) {
            int d = dh + it * 2;
            float e = 0.f;
#pragma unroll
            for (int hc = 0; hc < 16; hc++) e = fmaf(QW[hc][d], KW[hc][jj], e);
            E[d][j] = e;
        }
    }
    __syncthreads();
    if (tid < 64) {
        int d = tid;
        float mx = -INFINITY;
        for (int j2 = 0; j2 < 128; j2++) mx = fmaxf(mx, E[d][j2]);
        float l = 0.f;
        for (int j2 = 0; j2 < 128; j2++) l += expf(E[d][j2] - mx);
        float inv = 1.0f / l;
        for (int j2 = 0; j2 < 128; j2++) E[d][j2] = expf(E[d][j2] - mx) * inv;
    }
    __syncthreads();
#pragma unroll
    for (int t2 = 0; t2 < 4; t2++) {
        int idx = tid + t2 * 256;
        int hc = idx >> 6, dd = idx & 63;
        float oh = 0.f, ow = 0.f;
        for (int j2 = 0; j2 < 64; j2++) {
            oh = fmaf(VH[hc][j2], E[dd][j2],      oh);
            ow = fmaf(VW[hc][j2], E[dd][64 + j2], ow);
        }
        atomicAdd(&outsum[(b * 64 + hc * 4 + (dd >> 4)) * 4096
                          + ((((dd & 15) << 2) | n) << 6) + a], oh);
        atomicAdd(&outsum[(b * 64 + hc * 4 + nv) * 4096 + (dd << 6) + hv], ow);
    }
}

// ---------------------------------------------------------------- final conv + residual
__global__ __launch_bounds__(256) void final_kernel(
    const float* __restrict__ outsum, const float* __restrict__ wo,
    const float* __restrict__ bo, const float* __restrict__ gamma,
    const float* __restrict__ x, const float* __restrict__ PH,
    const float* __restrict__ PW, float* __restrict__ out) {
    __shared__ float st[64][65];
    int pt = blockIdx.x, mc = blockIdx.y, b = blockIdx.z;
    int tid = threadIdx.x;
#pragma unroll
    for (int it = 0; it < 16; it++) {
        int idx = tid + it * 256;
        int cl = idx >> 6, pl = idx & 63;
        st[cl][pl] = outsum[(b * 64 + cl) * 4096 + pt * 64 + pl];
    }
    __syncthreads();
    int ty = __builtin_amdgcn_readfirstlane(tid >> 6);
    int tx = tid & 63;
    float g = gamma[0];
    for (int i = 0; i < 32; i++) {
        int m = mc * 128 + ty * 32 + i;
        float acc = bo[m];
#pragma unroll
        for (int cl = 0; cl < 64; cl++)
            acc = fmaf(wo[m * 64 + cl], st[cl][tx], acc);
        int o = (b * 512 + m) * 4096 + pt * 64 + tx;
        out[o] = g * acc + x[o] + PH[m * 64 + pt] + PW[m * 64 + tx];
    }
}

// ---------------------------------------------------------------- launch
extern "C" void kernel_launch(void* const* d_in, const int* in_sizes, int n_in,
                              void* d_out, int out_size, void* d_ws, size_t ws_size,
                              hipStream_t stream) {
    const float* x     = (const float*)d_in[0];
    const float* wq    = (const float*)d_in[1];
    const float* bq    = (const float*)d_in[2];
    const float* wk    = (const float*)d_in[3];
    const float* bk    = (const float*)d_in[4];
    const float* wv    = (const float*)d_in[5];
    const float* bv    = (const float*)d_in[6];
    const float* wo    = (const float*)d_in[7];
    const float* bo    = (const float*)d_in[8];
    const float* gamma = (const float*)d_in[9];
    float* out = (float*)d_out;
    float* ws  = (float*)d_ws;

    float* PH = ws;                          // 32768 f32
    float* PW = PH + 32768;                  // 32768 f32
    u16*   WT = (u16*)(PW + 32768);          // 98304 bf16 (192x512)
    float* q  = (float*)(WT + 98304);        // 2M f32 each
    float* k  = q + 8 * 64 * 4096;
    float* v  = k + 8 * 64 * 4096;
    u16*   XT = (u16*)(v + 8 * 64 * 4096);   // 16.7M bf16 (33.5 MB)
    float* outsum = (float*)XT;              // aliased: XT dead after qkvm
    // total ws ~ 59 MB

    pos_kernel<<<dim3(512), dim3(64), 0, stream>>>(PH, PW);
    wconv_kernel<<<dim3(384), dim3(256), 0, stream>>>(wq, wk, wv, WT);
    xpose_kernel<<<dim3(8, 64, 8), dim3(256), 0, stream>>>(x, PH, PW, XT);
    qkvm_kernel<<<dim3(16, 3, 8), dim3(256), 0, stream>>>(XT, WT, bq, bk, bv, q, k, v);
    hipMemsetAsync(outsum, 0, (size_t)8 * 64 * 4096 * sizeof(float), stream);
    attn_kernel<<<dim3(64, 4, 8), dim3(256), 0, stream>>>(q, k, v, outsum);
    final_kernel<<<dim3(64, 4, 8), dim3(256), 0, stream>>>(outsum, wo, bo, gamma,
                                                           x, PH, PW, out);
}

// Round 3
// 314.080 us; speedup vs baseline: 2.8298x; 1.7693x over previous
//
#include <hip/hip_runtime.h>
#include <math.h>

// Problem constants: B=8, C=512, NH=4, H=W=64, CH=64, HC=16, P=H*W=4096

typedef unsigned int u32;
typedef unsigned short u16;
typedef __attribute__((ext_vector_type(8))) short short8;  // 8 bf16 = 4 VGPRs
typedef __attribute__((ext_vector_type(4))) float f32x4;

__device__ __forceinline__ u16 f2bf(float v) {
    u32 u = __float_as_uint(v);
    u32 r = (u + 0x7FFFu + ((u >> 16) & 1u)) >> 16;
    return (u16)r;
}

__device__ __forceinline__ void gll16(const void* g, void* l) {
    __builtin_amdgcn_global_load_lds(
        (const __attribute__((address_space(1))) u32*)g,
        (__attribute__((address_space(3))) u32*)l, 16, 0, 0);
}

// ---------------------------------------------------------------- pos tables
__global__ __launch_bounds__(64) void pos_kernel(float* __restrict__ PH,
                                                 float* __restrict__ PW) {
    const float r = 0.03597789207798663f; // ln(10000)/256
    int c = blockIdx.x;
    int t = threadIdx.x;
    int i = c >> 3;
    int j = ((c & 7) << 6) | t;
    float ph;
    if (j < 256) ph = sinf((float)i * expf(-(float)j * r));
    else         ph = cosf((float)i * expf(-(float)(j - 256) * r));
    PH[c * 64 + t] = ph;
    int tt = c >> 1;
    float dv = expf(-(float)tt * r);
    PW[c * 64 + t] = (c & 1) ? cosf((float)t * dv) : sinf((float)t * dv);
}

// ---------------------------------------------------------------- weights -> bf16
__global__ __launch_bounds__(256) void wconv_kernel(
    const float* __restrict__ wq, const float* __restrict__ wk,
    const float* __restrict__ wv, u16* __restrict__ WT) {
    int i = blockIdx.x * 256 + threadIdx.x;   // [0, 98304)
    float v;
    if (i < 32768)      v = wq[i];
    else if (i < 65536) v = wk[i - 32768];
    else                v = wv[i - 65536];
    WT[i] = f2bf(v);
}

// ---------------------------------------------------------------- x+pos -> XT bf16 [b][p][c]
__global__ __launch_bounds__(256) void xpose_kernel(
    const float* __restrict__ x, const float* __restrict__ PH,
    const float* __restrict__ PW, u16* __restrict__ XT) {
    __shared__ u16 T[64 * 68];
    int ct = blockIdx.x;  // c tile [0,8)
    int pt = blockIdx.y;  // h row  [0,64)
    int b  = blockIdx.z;
    int tid = threadIdx.x;
    int c0 = ct * 64;
    const size_t xb = ((size_t)b * 512 + c0) * 4096 + pt * 64;
#pragma unroll
    for (int it = 0; it < 16; ++it) {
        int idx = tid + it * 256;
        int cl = idx >> 6, pl = idx & 63;
        float v = x[xb + (size_t)cl * 4096 + pl]
                + PH[(c0 + cl) * 64 + pt] + PW[(c0 + cl) * 64 + pl];
        T[pl * 68 + cl] = f2bf(v);
    }
    __syncthreads();
#pragma unroll
    for (int jt = 0; jt < 4; ++jt) {
        int row = jt * 16 + (tid >> 4);
        int cq  = tid & 15;
        ushort4 val = *(const ushort4*)&T[row * 68 + cq * 4];
        *(ushort4*)&XT[((size_t)b * 4096 + pt * 64 + row) * 512 + c0 + cq * 4] = val;
    }
}

// ---------------------------------------------------------------- qkv GEMM via MFMA
// Writes bf16 q/k/v directly in attention layouts:
//  QHt/KHt [b][n][w][h][hc], QWt/KWt [b][n][h][w][hc], VHt [b][n][w][hc][h],
//  Vb natural [b][m][h][w]
__global__ __launch_bounds__(256) void qkvm_kernel(
    const u16* __restrict__ XT, const u16* __restrict__ WT,
    const float* __restrict__ bq, const float* __restrict__ bk,
    const float* __restrict__ bv,
    u16* __restrict__ QHt, u16* __restrict__ QWt,
    u16* __restrict__ KHt, u16* __restrict__ KWt,
    u16* __restrict__ VHt, u16* __restrict__ Vb) {
    __shared__ u16 Ab[64 * 64];    //  8 KB  [m][c]
    __shared__ u16 Bb[256 * 64];   // 32 KB  [p][c]
    int pt = blockIdx.x;   // [0,16)
    int mg = blockIdx.y;   // [0,3)  q/k/v
    int b  = blockIdx.z;
    int tid  = threadIdx.x;
    int w    = tid >> 6;
    int lane = tid & 63;
    int ln15 = lane & 15, quad = lane >> 4;
    int p0 = pt * 256;
    const u16* Wg = WT + mg * 64 * 512;
    const u16* Xg = XT + ((size_t)b * 4096 + p0) * 512;

    f32x4 acc[4][4];
#pragma unroll
    for (int mf = 0; mf < 4; ++mf)
#pragma unroll
        for (int pf = 0; pf < 4; ++pf)
            acc[mf][pf] = (f32x4){0.f, 0.f, 0.f, 0.f};

    for (int kc = 0; kc < 512; kc += 64) {
        __syncthreads();
#pragma unroll
        for (int it = 0; it < 2; ++it) {
            int idx = tid + it * 256;
            int r = idx >> 3, s = idx & 7;
            gll16(Wg + r * 512 + kc + s * 8, &Ab[idx * 8]);
        }
#pragma unroll
        for (int it = 0; it < 8; ++it) {
            int idx = tid + it * 256;
            int r = idx >> 3, s = idx & 7;
            gll16(Xg + (size_t)r * 512 + kc + s * 8, &Bb[idx * 8]);
        }
        __syncthreads();
#pragma unroll
        for (int ks = 0; ks < 2; ++ks) {
            short8 af[4], bf[4];
#pragma unroll
            for (int mf = 0; mf < 4; ++mf)
                af[mf] = *(const short8*)&Ab[(mf * 16 + ln15) * 64 + ks * 32 + quad * 8];
#pragma unroll
            for (int pf = 0; pf < 4; ++pf)
                bf[pf] = *(const short8*)&Bb[(w * 64 + pf * 16 + ln15) * 64 + ks * 32 + quad * 8];
#pragma unroll
            for (int mf = 0; mf < 4; ++mf)
#pragma unroll
                for (int pf = 0; pf < 4; ++pf)
                    acc[mf][pf] = __builtin_amdgcn_mfma_f32_16x16x32_bf16(
                        af[mf], bf[pf], acc[mf][pf], 0, 0, 0);
        }
    }

    const float* bias = (mg == 0) ? bq : (mg == 1) ? bk : bv;
    if (mg == 2) {
#pragma unroll
        for (int mf = 0; mf < 4; ++mf)
#pragma unroll
            for (int pf = 0; pf < 4; ++pf) {
                int p = p0 + w * 64 + pf * 16 + ln15;
                int h = p >> 6, wc = p & 63;
#pragma unroll
                for (int reg = 0; reg < 4; ++reg) {
                    int hc = quad * 4 + reg;
                    int m  = mf * 16 + hc;
                    u16 bfv = f2bf(acc[mf][pf][reg] + bias[m]);
                    VHt[(((b * 4 + mf) * 64 + wc) * 16 + hc) * 64 + h] = bfv;
                    Vb[((size_t)(b * 64 + m)) * 4096 + p] = bfv;
                }
            }
    } else {
        u16* Ht = (mg == 1) ? KHt : QHt;
        u16* Wt = (mg == 1) ? KWt : QWt;
#pragma unroll
        for (int mf = 0; mf < 4; ++mf)
#pragma unroll
            for (int pf = 0; pf < 4; ++pf) {
                int p = p0 + w * 64 + pf * 16 + ln15;
                int h = p >> 6, wc = p & 63;
                ushort4 pk;
                pk.x = f2bf(acc[mf][pf][0] + bias[mf * 16 + quad * 4 + 0]);
                pk.y = f2bf(acc[mf][pf][1] + bias[mf * 16 + quad * 4 + 1]);
                pk.z = f2bf(acc[mf][pf][2] + bias[mf * 16 + quad * 4 + 2]);
                pk.w = f2bf(acc[mf][pf][3] + bias[mf * 16 + quad * 4 + 3]);
                *(ushort4*)&Ht[(((b * 4 + mf) * 64 + wc) * 64 + h) * 16 + quad * 4] = pk;
                *(ushort4*)&Wt[(((b * 4 + mf) * 64 + h) * 64 + wc) * 16 + quad * 4] = pk;
            }
    }
}

// ---------------------------------------------------------------- fused attention (MFMA)
// Block (b,a,n): one 64x128 logit matrix via one K=32 MFMA pass (QH||QW vs
// KH||0 / 0||KW), in-register softmax (wave owns 16 complete rows), P->LDS
// bf16, PV via MFMA, single-writer scatter stores to OH/OW.
__global__ __launch_bounds__(256, 4) void attn_kernel(
    const u16* __restrict__ QHt, const u16* __restrict__ QWt,
    const u16* __restrict__ KHt, const u16* __restrict__ KWt,
    const u16* __restrict__ VHt, const u16* __restrict__ Vb,
    float* __restrict__ OH, float* __restrict__ OW) {
    __shared__ u16 A_lds[64 * 40];     // [d][k32]  k<16=QH, k>=16=QW
    __shared__ u16 B_lds[128 * 40];    // [j][k32]  j<64:KH||0, j>=64:0||KW
    __shared__ u16 VH_lds[16 * 72];    // [hc][h]
    __shared__ u16 VW_lds[16 * 72];    // [hc][w]
    __shared__ u16 P_lds[64 * 144];    // [d][j]  bf16 probabilities

    int a = blockIdx.x, n = blockIdx.y, b = blockIdx.z;
    int tid  = threadIdx.x;
    int w    = tid >> 6;
    int lane = tid & 63;
    int ln15 = lane & 15, quad = lane >> 4;
    int nv = a >> 4;
    int hv = ((a & 15) << 2) | n;

    const int cb = ((b * 4 + n) * 64 + a) << 10;   // 1024-elem chunk base
    const u16* vb = Vb + ((size_t)(b * 64 + nv * 16)) * 4096 + hv * 64;

    {
        int t = tid & 127;
        const short8 z8 = {0, 0, 0, 0, 0, 0, 0, 0};
        if (tid < 128) {
            short8 vA = *(const short8*)(QHt + cb + t * 8);
            *(short8*)&A_lds[(t >> 1) * 40 + (t & 1) * 8] = vA;
            short8 vK = *(const short8*)(KHt + cb + t * 8);
            *(short8*)&B_lds[(t >> 1) * 40 + (t & 1) * 8] = vK;
            *(short8*)&B_lds[(t >> 1) * 40 + 16 + (t & 1) * 8] = z8;
            short8 vV = *(const short8*)(VHt + cb + t * 8);
            *(short8*)&VH_lds[(t >> 3) * 72 + (t & 7) * 8] = vV;
        } else {
            short8 vA = *(const short8*)(QWt + cb + t * 8);
            *(short8*)&A_lds[(t >> 1) * 40 + 16 + (t & 1) * 8] = vA;
            short8 vK = *(const short8*)(KWt + cb + t * 8);
            *(short8*)&B_lds[(64 + (t >> 1)) * 40 + 16 + (t & 1) * 8] = vK;
            *(short8*)&B_lds[(64 + (t >> 1)) * 40 + (t & 1) * 8] = z8;
            short8 vV = *(const short8*)(vb + (t >> 3) * 4096 + (t & 7) * 8);
            *(short8*)&VW_lds[(t >> 3) * 72 + (t & 7) * 8] = vV;
        }
    }
    __syncthreads();

    // ---- energies: wave w computes rows d in [w*16, w*16+16), all 128 j
    const f32x4 zf = {0.f, 0.f, 0.f, 0.f};
    short8 af = *(const short8*)&A_lds[(w * 16 + ln15) * 40 + quad * 8];
    f32x4 acc[8];
#pragma unroll
    for (int nt = 0; nt < 8; ++nt) {
        short8 bf = *(const short8*)&B_lds[(nt * 16 + ln15) * 40 + quad * 8];
        acc[nt] = __builtin_amdgcn_mfma_f32_16x16x32_bf16(af, bf, zf, 0, 0, 0);
    }
    // lane holds E[d = w*16+quad*4+reg][j = nt*16+ln15]

    // ---- diagonal mask (H half only, j<64)
#pragma unroll
    for (int nt = 0; nt < 4; ++nt)
#pragma unroll
        for (int r = 0; r < 4; ++r)
            if (nt * 16 + ln15 == w * 16 + quad * 4 + r) acc[nt][r] = -1e30f;

    // ---- in-register softmax: reduce over ln15 (16-lane group) per row
    float inv[4];
#pragma unroll
    for (int r = 0; r < 4; ++r) {
        float mrow = acc[0][r];
#pragma unroll
        for (int nt = 1; nt < 8; ++nt) mrow = fmaxf(mrow, acc[nt][r]);
        mrow = fmaxf(mrow, __shfl_xor(mrow, 1, 64));
        mrow = fmaxf(mrow, __shfl_xor(mrow, 2, 64));
        mrow = fmaxf(mrow, __shfl_xor(mrow, 4, 64));
        mrow = fmaxf(mrow, __shfl_xor(mrow, 8, 64));
        float s = 0.f;
#pragma unroll
        for (int nt = 0; nt < 8; ++nt) {
            float e = __expf(acc[nt][r] - mrow);
            acc[nt][r] = e;
            s += e;
        }
        s += __shfl_xor(s, 1, 64);
        s += __shfl_xor(s, 2, 64);
        s += __shfl_xor(s, 4, 64);
        s += __shfl_xor(s, 8, 64);
        inv[r] = 1.0f / s;
    }
#pragma unroll
    for (int nt = 0; nt < 8; ++nt)
#pragma unroll
        for (int r = 0; r < 4; ++r)
            P_lds[(w * 16 + quad * 4 + r) * 144 + nt * 16 + ln15] =
                f2bf(acc[nt][r] * inv[r]);
    __syncthreads();

    // ---- PV: out[dd][hc], wave w owns dd in [w*16, w*16+16)
    int prow = (w * 16 + ln15) * 144;
    short8 a0 = *(const short8*)&P_lds[prow +       quad * 8];
    short8 a1 = *(const short8*)&P_lds[prow + 32  + quad * 8];
    short8 a2 = *(const short8*)&P_lds[prow + 64  + quad * 8];
    short8 a3 = *(const short8*)&P_lds[prow + 96  + quad * 8];
    short8 b0 = *(const short8*)&VH_lds[ln15 * 72 +      quad * 8];
    short8 b1 = *(const short8*)&VH_lds[ln15 * 72 + 32 + quad * 8];
    short8 c0 = *(const short8*)&VW_lds[ln15 * 72 +      quad * 8];
    short8 c1 = *(const short8*)&VW_lds[ln15 * 72 + 32 + quad * 8];
    f32x4 oH = __builtin_amdgcn_mfma_f32_16x16x32_bf16(a0, b0, zf, 0, 0, 0);
    oH = __builtin_amdgcn_mfma_f32_16x16x32_bf16(a1, b1, oH, 0, 0, 0);
    f32x4 oW = __builtin_amdgcn_mfma_f32_16x16x32_bf16(a2, c0, zf, 0, 0, 0);
    oW = __builtin_amdgcn_mfma_f32_16x16x32_bf16(a3, c1, oW, 0, 0, 0);

    // lane holds out[dd = w*16+quad*4+reg][hc = ln15]; single-writer stores
#pragma unroll
    for (int r = 0; r < 4; ++r) {
        int dl = quad * 4 + r;           // dd & 15
        // H: c' = hc*4 + w, h' = dl*4 + n, w' = a
        OH[((b * 64 + ln15 * 4 + w) * 64 + dl * 4 + n) * 64 + a] = oH[r];
        // W: c' = hc*4 + nv, h' = dd, w' = hv
        OW[((b * 64 + ln15 * 4 + nv) * 64 + w * 16 + dl) * 64 + hv] = oW[r];
    }
}

// ---------------------------------------------------------------- final conv + residual
__global__ __launch_bounds__(256) void final_kernel(
    const float* __restrict__ OH, const float* __restrict__ OW,
    const float* __restrict__ wo, const float* __restrict__ bo,
    const float* __restrict__ gamma, const float* __restrict__ x,
    const float* __restrict__ PH, const float* __restrict__ PW,
    float* __restrict__ out) {
    __shared__ float st[64][65];
    int pt = blockIdx.x, mc = blockIdx.y, b = blockIdx.z;
    int tid = threadIdx.x;
#pragma unroll
    for (int it = 0; it < 16; it++) {
        int idx = tid + it * 256;
        int cl = idx >> 6, pl = idx & 63;
        int o = (b * 64 + cl) * 4096 + pt * 64 + pl;
        st[cl][pl] = OH[o] + OW[o];
    }
    __syncthreads();
    int ty = __builtin_amdgcn_readfirstlane(tid >> 6);
    int tx = tid & 63;
    float g = gamma[0];
    for (int i = 0; i < 32; i++) {
        int m = mc * 128 + ty * 32 + i;
        float acc = bo[m];
#pragma unroll
        for (int cl = 0; cl < 64; cl++)
            acc = fmaf(wo[m * 64 + cl], st[cl][tx], acc);
        int o = (b * 512 + m) * 4096 + pt * 64 + tx;
        out[o] = g * acc + x[o] + PH[m * 64 + pt] + PW[m * 64 + tx];
    }
}

// ---------------------------------------------------------------- launch
extern "C" void kernel_launch(void* const* d_in, const int* in_sizes, int n_in,
                              void* d_out, int out_size, void* d_ws, size_t ws_size,
                              hipStream_t stream) {
    const float* x     = (const float*)d_in[0];
    const float* wq    = (const float*)d_in[1];
    const float* bq    = (const float*)d_in[2];
    const float* wk    = (const float*)d_in[3];
    const float* bk    = (const float*)d_in[4];
    const float* wv    = (const float*)d_in[5];
    const float* bv    = (const float*)d_in[6];
    const float* wo    = (const float*)d_in[7];
    const float* bo    = (const float*)d_in[8];
    const float* gamma = (const float*)d_in[9];
    float* out = (float*)d_out;
    float* ws  = (float*)d_ws;

    float* PH = ws;                           // 32768 f32
    float* PW = PH + 32768;                   // 32768 f32
    u16*   WT  = (u16*)(PW + 32768);          // 98304
    u16*   XT  = WT + 98304;                  // 16777216 (33.5 MB)
    u16*   QHt = XT + 16777216;               // 2097152 each (4.2 MB)
    u16*   QWt = QHt + 2097152;
    u16*   KHt = QWt + 2097152;
    u16*   KWt = KHt + 2097152;
    u16*   VHt = KWt + 2097152;
    u16*   Vb  = VHt + 2097152;
    float* OH  = (float*)XT;                  // alias: XT dead after qkvm
    float* OW  = OH + 2097152;
    // total ws ~ 59.2 MB

    pos_kernel<<<dim3(512), dim3(64), 0, stream>>>(PH, PW);
    wconv_kernel<<<dim3(384), dim3(256), 0, stream>>>(wq, wk, wv, WT);
    xpose_kernel<<<dim3(8, 64, 8), dim3(256), 0, stream>>>(x, PH, PW, XT);
    qkvm_kernel<<<dim3(16, 3, 8), dim3(256), 0, stream>>>(
        XT, WT, bq, bk, bv, QHt, QWt, KHt, KWt, VHt, Vb);
    attn_kernel<<<dim3(64, 4, 8), dim3(256), 0, stream>>>(
        QHt, QWt, KHt, KWt, VHt, Vb, OH, OW);
    final_kernel<<<dim3(64, 4, 8), dim3(256), 0, stream>>>(
        OH, OW, wo, bo, gamma, x, PH, PW, out);
}

// Round 4
// 262.357 us; speedup vs baseline: 3.3877x; 1.1971x over previous
//
#include <hip/hip_runtime.h>
#include <math.h>

// Problem constants: B=8, C=512, NH=4, H=W=64, CH=64, HC=16, P=H*W=4096

typedef unsigned int u32;
typedef unsigned short u16;
typedef __attribute__((ext_vector_type(8))) short short8;  // 8 bf16 = 4 VGPRs
typedef __attribute__((ext_vector_type(4))) float f32x4;

__device__ __forceinline__ u16 f2bf(float v) {
    u32 u = __float_as_uint(v);
    u32 r = (u + 0x7FFFu + ((u >> 16) & 1u)) >> 16;
    return (u16)r;
}

__device__ __forceinline__ void gll16(const void* g, void* l) {
    __builtin_amdgcn_global_load_lds(
        (const __attribute__((address_space(1))) u32*)g,
        (__attribute__((address_space(3))) u32*)l, 16, 0, 0);
}

// ---------------------------------------------------------------- pos tables
__global__ __launch_bounds__(64) void pos_kernel(float* __restrict__ PH,
                                                 float* __restrict__ PW) {
    const float r = 0.03597789207798663f; // ln(10000)/256
    int c = blockIdx.x;
    int t = threadIdx.x;
    int i = c >> 3;
    int j = ((c & 7) << 6) | t;
    float ph;
    if (j < 256) ph = sinf((float)i * expf(-(float)j * r));
    else         ph = cosf((float)i * expf(-(float)(j - 256) * r));
    PH[c * 64 + t] = ph;
    int tt = c >> 1;
    float dv = expf(-(float)tt * r);
    PW[c * 64 + t] = (c & 1) ? cosf((float)t * dv) : sinf((float)t * dv);
}

// ---------------------------------------------------------------- weights -> bf16
// WT[192][512] = wq|wk|wv ; WOb[512][64] = wo
__global__ __launch_bounds__(256) void wconv_kernel(
    const float* __restrict__ wq, const float* __restrict__ wk,
    const float* __restrict__ wv, const float* __restrict__ wo,
    u16* __restrict__ WT, u16* __restrict__ WOb) {
    int i = blockIdx.x * 256 + threadIdx.x;   // [0, 131072)
    if (i < 98304) {
        float v;
        if (i < 32768)      v = wq[i];
        else if (i < 65536) v = wk[i - 32768];
        else                v = wv[i - 65536];
        WT[i] = f2bf(v);
    } else {
        WOb[i - 98304] = f2bf(wo[i - 98304]);
    }
}

// ---------------------------------------------------------------- x+pos -> XT bf16 [b][p][c]
__global__ __launch_bounds__(256) void xpose_kernel(
    const float* __restrict__ x, const float* __restrict__ PH,
    const float* __restrict__ PW, u16* __restrict__ XT) {
    __shared__ u16 T[64 * 68];
    int ct = blockIdx.x;  // c tile [0,8)
    int pt = blockIdx.y;  // h row  [0,64)
    int b  = blockIdx.z;
    int tid = threadIdx.x;
    int c0 = ct * 64;
    const size_t xb = ((size_t)b * 512 + c0) * 4096 + pt * 64;
#pragma unroll
    for (int it = 0; it < 16; ++it) {
        int idx = tid + it * 256;
        int cl = idx >> 6, pl = idx & 63;
        float v = x[xb + (size_t)cl * 4096 + pl]
                + PH[(c0 + cl) * 64 + pt] + PW[(c0 + cl) * 64 + pl];
        T[pl * 68 + cl] = f2bf(v);
    }
    __syncthreads();
#pragma unroll
    for (int jt = 0; jt < 4; ++jt) {
        int row = jt * 16 + (tid >> 4);
        int cq  = tid & 15;
        ushort4 val = *(const ushort4*)&T[row * 68 + cq * 4];
        *(ushort4*)&XT[((size_t)b * 4096 + pt * 64 + row) * 512 + c0 + cq * 4] = val;
    }
}

// ---------------------------------------------------------------- qkv GEMM via MFMA
__global__ __launch_bounds__(256) void qkvm_kernel(
    const u16* __restrict__ XT, const u16* __restrict__ WT,
    const float* __restrict__ bq, const float* __restrict__ bk,
    const float* __restrict__ bv,
    u16* __restrict__ QHt, u16* __restrict__ QWt,
    u16* __restrict__ KHt, u16* __restrict__ KWt,
    u16* __restrict__ VHt, u16* __restrict__ Vb) {
    __shared__ u16 Ab[64 * 64];    //  8 KB  [m][c]
    __shared__ u16 Bb[256 * 64];   // 32 KB  [p][c]
    int pt = blockIdx.x;   // [0,16)
    int mg = blockIdx.y;   // [0,3)  q/k/v
    int b  = blockIdx.z;
    int tid  = threadIdx.x;
    int w    = tid >> 6;
    int lane = tid & 63;
    int ln15 = lane & 15, quad = lane >> 4;
    int p0 = pt * 256;
    const u16* Wg = WT + mg * 64 * 512;
    const u16* Xg = XT + ((size_t)b * 4096 + p0) * 512;

    f32x4 acc[4][4];
#pragma unroll
    for (int mf = 0; mf < 4; ++mf)
#pragma unroll
        for (int pf = 0; pf < 4; ++pf)
            acc[mf][pf] = (f32x4){0.f, 0.f, 0.f, 0.f};

    for (int kc = 0; kc < 512; kc += 64) {
        __syncthreads();
#pragma unroll
        for (int it = 0; it < 2; ++it) {
            int idx = tid + it * 256;
            int r = idx >> 3, s = idx & 7;
            gll16(Wg + r * 512 + kc + s * 8, &Ab[idx * 8]);
        }
#pragma unroll
        for (int it = 0; it < 8; ++it) {
            int idx = tid + it * 256;
            int r = idx >> 3, s = idx & 7;
            gll16(Xg + (size_t)r * 512 + kc + s * 8, &Bb[idx * 8]);
        }
        __syncthreads();
#pragma unroll
        for (int ks = 0; ks < 2; ++ks) {
            short8 af[4], bf[4];
#pragma unroll
            for (int mf = 0; mf < 4; ++mf)
                af[mf] = *(const short8*)&Ab[(mf * 16 + ln15) * 64 + ks * 32 + quad * 8];
#pragma unroll
            for (int pf = 0; pf < 4; ++pf)
                bf[pf] = *(const short8*)&Bb[(w * 64 + pf * 16 + ln15) * 64 + ks * 32 + quad * 8];
#pragma unroll
            for (int mf = 0; mf < 4; ++mf)
#pragma unroll
                for (int pf = 0; pf < 4; ++pf)
                    acc[mf][pf] = __builtin_amdgcn_mfma_f32_16x16x32_bf16(
                        af[mf], bf[pf], acc[mf][pf], 0, 0, 0);
        }
    }

    const float* bias = (mg == 0) ? bq : (mg == 1) ? bk : bv;
    if (mg == 2) {
#pragma unroll
        for (int mf = 0; mf < 4; ++mf)
#pragma unroll
            for (int pf = 0; pf < 4; ++pf) {
                int p = p0 + w * 64 + pf * 16 + ln15;
                int h = p >> 6, wc = p & 63;
#pragma unroll
                for (int reg = 0; reg < 4; ++reg) {
                    int hc = quad * 4 + reg;
                    int m  = mf * 16 + hc;
                    u16 bfv = f2bf(acc[mf][pf][reg] + bias[m]);
                    VHt[(((b * 4 + mf) * 64 + wc) * 16 + hc) * 64 + h] = bfv;
                    Vb[((size_t)(b * 64 + m)) * 4096 + p] = bfv;
                }
            }
    } else {
        u16* Ht = (mg == 1) ? KHt : QHt;
        u16* Wt = (mg == 1) ? KWt : QWt;
#pragma unroll
        for (int mf = 0; mf < 4; ++mf)
#pragma unroll
            for (int pf = 0; pf < 4; ++pf) {
                int p = p0 + w * 64 + pf * 16 + ln15;
                int h = p >> 6, wc = p & 63;
                ushort4 pk;
                pk.x = f2bf(acc[mf][pf][0] + bias[mf * 16 + quad * 4 + 0]);
                pk.y = f2bf(acc[mf][pf][1] + bias[mf * 16 + quad * 4 + 1]);
                pk.z = f2bf(acc[mf][pf][2] + bias[mf * 16 + quad * 4 + 2]);
                pk.w = f2bf(acc[mf][pf][3] + bias[mf * 16 + quad * 4 + 3]);
                *(ushort4*)&Ht[(((b * 4 + mf) * 64 + wc) * 64 + h) * 16 + quad * 4] = pk;
                *(ushort4*)&Wt[(((b * 4 + mf) * 64 + h) * 64 + wc) * 16 + quad * 4] = pk;
            }
    }
}

// ---------------------------------------------------------------- fused attention (MFMA)
__global__ __launch_bounds__(256, 4) void attn_kernel(
    const u16* __restrict__ QHt, const u16* __restrict__ QWt,
    const u16* __restrict__ KHt, const u16* __restrict__ KWt,
    const u16* __restrict__ VHt, const u16* __restrict__ Vb,
    float* __restrict__ OH, float* __restrict__ OW) {
    __shared__ u16 A_lds[64 * 40];
    __shared__ u16 B_lds[128 * 40];
    __shared__ u16 VH_lds[16 * 72];
    __shared__ u16 VW_lds[16 * 72];
    __shared__ u16 P_lds[64 * 144];

    int a = blockIdx.x, n = blockIdx.y, b = blockIdx.z;
    int tid  = threadIdx.x;
    int w    = tid >> 6;
    int lane = tid & 63;
    int ln15 = lane & 15, quad = lane >> 4;
    int nv = a >> 4;
    int hv = ((a & 15) << 2) | n;

    const int cb = ((b * 4 + n) * 64 + a) << 10;
    const u16* vb = Vb + ((size_t)(b * 64 + nv * 16)) * 4096 + hv * 64;

    {
        int t = tid & 127;
        const short8 z8 = {0, 0, 0, 0, 0, 0, 0, 0};
        if (tid < 128) {
            short8 vA = *(const short8*)(QHt + cb + t * 8);
            *(short8*)&A_lds[(t >> 1) * 40 + (t & 1) * 8] = vA;
            short8 vK = *(const short8*)(KHt + cb + t * 8);
            *(short8*)&B_lds[(t >> 1) * 40 + (t & 1) * 8] = vK;
            *(short8*)&B_lds[(t >> 1) * 40 + 16 + (t & 1) * 8] = z8;
            short8 vV = *(const short8*)(VHt + cb + t * 8);
            *(short8*)&VH_lds[(t >> 3) * 72 + (t & 7) * 8] = vV;
        } else {
            short8 vA = *(const short8*)(QWt + cb + t * 8);
            *(short8*)&A_lds[(t >> 1) * 40 + 16 + (t & 1) * 8] = vA;
            short8 vK = *(const short8*)(KWt + cb + t * 8);
            *(short8*)&B_lds[(64 + (t >> 1)) * 40 + 16 + (t & 1) * 8] = vK;
            *(short8*)&B_lds[(64 + (t >> 1)) * 40 + (t & 1) * 8] = z8;
            short8 vV = *(const short8*)(vb + (t >> 3) * 4096 + (t & 7) * 8);
            *(short8*)&VW_lds[(t >> 3) * 72 + (t & 7) * 8] = vV;
        }
    }
    __syncthreads();

    const f32x4 zf = {0.f, 0.f, 0.f, 0.f};
    short8 af = *(const short8*)&A_lds[(w * 16 + ln15) * 40 + quad * 8];
    f32x4 acc[8];
#pragma unroll
    for (int nt = 0; nt < 8; ++nt) {
        short8 bf = *(const short8*)&B_lds[(nt * 16 + ln15) * 40 + quad * 8];
        acc[nt] = __builtin_amdgcn_mfma_f32_16x16x32_bf16(af, bf, zf, 0, 0, 0);
    }

#pragma unroll
    for (int nt = 0; nt < 4; ++nt)
#pragma unroll
        for (int r = 0; r < 4; ++r)
            if (nt * 16 + ln15 == w * 16 + quad * 4 + r) acc[nt][r] = -1e30f;

    float inv[4];
#pragma unroll
    for (int r = 0; r < 4; ++r) {
        float mrow = acc[0][r];
#pragma unroll
        for (int nt = 1; nt < 8; ++nt) mrow = fmaxf(mrow, acc[nt][r]);
        mrow = fmaxf(mrow, __shfl_xor(mrow, 1, 64));
        mrow = fmaxf(mrow, __shfl_xor(mrow, 2, 64));
        mrow = fmaxf(mrow, __shfl_xor(mrow, 4, 64));
        mrow = fmaxf(mrow, __shfl_xor(mrow, 8, 64));
        float s = 0.f;
#pragma unroll
        for (int nt = 0; nt < 8; ++nt) {
            float e = __expf(acc[nt][r] - mrow);
            acc[nt][r] = e;
            s += e;
        }
        s += __shfl_xor(s, 1, 64);
        s += __shfl_xor(s, 2, 64);
        s += __shfl_xor(s, 4, 64);
        s += __shfl_xor(s, 8, 64);
        inv[r] = 1.0f / s;
    }
#pragma unroll
    for (int nt = 0; nt < 8; ++nt)
#pragma unroll
        for (int r = 0; r < 4; ++r)
            P_lds[(w * 16 + quad * 4 + r) * 144 + nt * 16 + ln15] =
                f2bf(acc[nt][r] * inv[r]);
    __syncthreads();

    int prow = (w * 16 + ln15) * 144;
    short8 a0 = *(const short8*)&P_lds[prow +       quad * 8];
    short8 a1 = *(const short8*)&P_lds[prow + 32  + quad * 8];
    short8 a2 = *(const short8*)&P_lds[prow + 64  + quad * 8];
    short8 a3 = *(const short8*)&P_lds[prow + 96  + quad * 8];
    short8 b0 = *(const short8*)&VH_lds[ln15 * 72 +      quad * 8];
    short8 b1 = *(const short8*)&VH_lds[ln15 * 72 + 32 + quad * 8];
    short8 c0 = *(const short8*)&VW_lds[ln15 * 72 +      quad * 8];
    short8 c1 = *(const short8*)&VW_lds[ln15 * 72 + 32 + quad * 8];
    f32x4 oH = __builtin_amdgcn_mfma_f32_16x16x32_bf16(a0, b0, zf, 0, 0, 0);
    oH = __builtin_amdgcn_mfma_f32_16x16x32_bf16(a1, b1, oH, 0, 0, 0);
    f32x4 oW = __builtin_amdgcn_mfma_f32_16x16x32_bf16(a2, c0, zf, 0, 0, 0);
    oW = __builtin_amdgcn_mfma_f32_16x16x32_bf16(a3, c1, oW, 0, 0, 0);

#pragma unroll
    for (int r = 0; r < 4; ++r) {
        int dl = quad * 4 + r;
        OH[((b * 64 + ln15 * 4 + w) * 64 + dl * 4 + n) * 64 + a] = oH[r];
        OW[((b * 64 + ln15 * 4 + nv) * 64 + w * 16 + dl) * 64 + hv] = oW[r];
    }
}

// ---------------------------------------------------------------- OH+OW -> Sb bf16 [b][p][c]
__global__ __launch_bounds__(256) void sconv_kernel(
    const float* __restrict__ OH, const float* __restrict__ OW,
    u16* __restrict__ Sb) {
    __shared__ u16 T[64 * 68];
    int pt = blockIdx.x;  // h row [0,64)
    int b  = blockIdx.y;
    int tid = threadIdx.x;
#pragma unroll
    for (int it = 0; it < 16; ++it) {
        int idx = tid + it * 256;
        int cl = idx >> 6, pl = idx & 63;
        int o = (b * 64 + cl) * 4096 + pt * 64 + pl;
        T[pl * 68 + cl] = f2bf(OH[o] + OW[o]);
    }
    __syncthreads();
#pragma unroll
    for (int jt = 0; jt < 4; ++jt) {
        int row = jt * 16 + (tid >> 4);
        int cq  = tid & 15;
        ushort4 val = *(const ushort4*)&T[row * 68 + cq * 4];
        *(ushort4*)&Sb[((size_t)b * 4096 + pt * 64 + row) * 64 + cq * 4] = val;
    }
}

// ---------------------------------------------------------------- final conv via MFMA
// out[b][m][p] = g*(sum_c WOb[m][c]*Sb[b][p][c] + bo[m]) + x[b][m][p] + pos
__global__ __launch_bounds__(256) void finalm_kernel(
    const u16* __restrict__ Sb, const u16* __restrict__ WOb,
    const float* __restrict__ bo, const float* __restrict__ gamma,
    const float* __restrict__ x, const float* __restrict__ PH,
    const float* __restrict__ PW, float* __restrict__ out) {
    __shared__ u16 Ab[64 * 64];    //  8 KB  [m][c]
    __shared__ u16 Bb[256 * 64];   // 32 KB  [p][c]
    int pt = blockIdx.x;   // [0,16)
    int mc = blockIdx.y;   // [0,8)
    int b  = blockIdx.z;
    int tid  = threadIdx.x;
    int w    = tid >> 6;
    int lane = tid & 63;
    int ln15 = lane & 15, quad = lane >> 4;
    int p0 = pt * 256, m0 = mc * 64;
    const u16* Ag = WOb + m0 * 64;
    const u16* Sg = Sb + ((size_t)b * 4096 + p0) * 64;

#pragma unroll
    for (int it = 0; it < 2; ++it) {
        int idx = tid + it * 256;
        gll16(Ag + idx * 8, &Ab[idx * 8]);
    }
#pragma unroll
    for (int it = 0; it < 8; ++it) {
        int idx = tid + it * 256;
        gll16(Sg + idx * 8, &Bb[idx * 8]);
    }
    __syncthreads();

    const f32x4 zf = {0.f, 0.f, 0.f, 0.f};
    f32x4 acc[4][4];
#pragma unroll
    for (int mf = 0; mf < 4; ++mf)
#pragma unroll
        for (int pf = 0; pf < 4; ++pf)
            acc[mf][pf] = zf;
#pragma unroll
    for (int ks = 0; ks < 2; ++ks) {
        short8 af[4], bf[4];
#pragma unroll
        for (int mf = 0; mf < 4; ++mf)
            af[mf] = *(const short8*)&Ab[(mf * 16 + ln15) * 64 + ks * 32 + quad * 8];
#pragma unroll
        for (int pf = 0; pf < 4; ++pf)
            bf[pf] = *(const short8*)&Bb[(w * 64 + pf * 16 + ln15) * 64 + ks * 32 + quad * 8];
#pragma unroll
        for (int mf = 0; mf < 4; ++mf)
#pragma unroll
            for (int pf = 0; pf < 4; ++pf)
                acc[mf][pf] = __builtin_amdgcn_mfma_f32_16x16x32_bf16(
                    af[mf], bf[pf], acc[mf][pf], 0, 0, 0);
    }

    float g = gamma[0];
    int h = pt * 4 + w;   // wave-uniform: p>>6
#pragma unroll
    for (int mf = 0; mf < 4; ++mf)
#pragma unroll
        for (int pf = 0; pf < 4; ++pf) {
            int p  = p0 + w * 64 + pf * 16 + ln15;
            int wv = pf * 16 + ln15;  // p & 63
#pragma unroll
            for (int reg = 0; reg < 4; ++reg) {
                int m = m0 + mf * 16 + quad * 4 + reg;
                size_t o = ((size_t)(b * 512 + m)) * 4096 + p;
                out[o] = g * (acc[mf][pf][reg] + bo[m]) + x[o]
                       + PH[m * 64 + h] + PW[m * 64 + wv];
            }
        }
}

// ---------------------------------------------------------------- launch
extern "C" void kernel_launch(void* const* d_in, const int* in_sizes, int n_in,
                              void* d_out, int out_size, void* d_ws, size_t ws_size,
                              hipStream_t stream) {
    const float* x     = (const float*)d_in[0];
    const float* wq    = (const float*)d_in[1];
    const float* bq    = (const float*)d_in[2];
    const float* wk    = (const float*)d_in[3];
    const float* bk    = (const float*)d_in[4];
    const float* wv    = (const float*)d_in[5];
    const float* bv    = (const float*)d_in[6];
    const float* wo    = (const float*)d_in[7];
    const float* bo    = (const float*)d_in[8];
    const float* gamma = (const float*)d_in[9];
    float* out = (float*)d_out;
    float* ws  = (float*)d_ws;

    float* PH = ws;                           // 32768 f32
    float* PW = PH + 32768;                   // 32768 f32
    u16*   WT  = (u16*)(PW + 32768);          // 98304
    u16*   WOb = WT + 98304;                  // 32768
    u16*   XT  = WOb + 32768;                 // 16777216 (33.5 MB)
    u16*   QHt = XT + 16777216;               // 2097152 each (4.2 MB)
    u16*   QWt = QHt + 2097152;
    u16*   KHt = QWt + 2097152;
    u16*   KWt = KHt + 2097152;
    u16*   VHt = KWt + 2097152;
    u16*   Vb  = VHt + 2097152;
    // aliases into XT region (XT dead after qkvm): OH|OW|Sb = 8.4+8.4+4.2 MB < 33.5 MB
    float* OH  = (float*)XT;
    float* OW  = OH + 2097152;
    u16*   Sbb = (u16*)(OW + 2097152);
    // total ws ~ 59.3 MB

    pos_kernel<<<dim3(512), dim3(64), 0, stream>>>(PH, PW);
    wconv_kernel<<<dim3(512), dim3(256), 0, stream>>>(wq, wk, wv, wo, WT, WOb);
    xpose_kernel<<<dim3(8, 64, 8), dim3(256), 0, stream>>>(x, PH, PW, XT);
    qkvm_kernel<<<dim3(16, 3, 8), dim3(256), 0, stream>>>(
        XT, WT, bq, bk, bv, QHt, QWt, KHt, KWt, VHt, Vb);
    attn_kernel<<<dim3(64, 4, 8), dim3(256), 0, stream>>>(
        QHt, QWt, KHt, KWt, VHt, Vb, OH, OW);
    sconv_kernel<<<dim3(64, 8), dim3(256), 0, stream>>>(OH, OW, Sbb);
    finalm_kernel<<<dim3(16, 8, 8), dim3(256), 0, stream>>>(
        Sbb, WOb, bo, gamma, x, PH, PW, out);
}

// Round 5
// 249.319 us; speedup vs baseline: 3.5648x; 1.0523x over previous
//
#include <hip/hip_runtime.h>
#include <math.h>

// Problem constants: B=8, C=512, NH=4, H=W=64, CH=64, HC=16, P=H*W=4096

typedef unsigned int u32;
typedef unsigned short u16;
typedef __attribute__((ext_vector_type(8))) short short8;  // 8 bf16 = 4 VGPRs
typedef __attribute__((ext_vector_type(4))) float f32x4;

__device__ __forceinline__ u16 f2bf(float v) {
    u32 u = __float_as_uint(v);
    u32 r = (u + 0x7FFFu + ((u >> 16) & 1u)) >> 16;
    return (u16)r;
}

__device__ __forceinline__ void gll16(const void* g, void* l) {
    __builtin_amdgcn_global_load_lds(
        (const __attribute__((address_space(1))) u32*)g,
        (__attribute__((address_space(3))) u32*)l, 16, 0, 0);
}

// ---------------------------------------------------------------- pos tables
__global__ __launch_bounds__(64) void pos_kernel(float* __restrict__ PH,
                                                 float* __restrict__ PW) {
    const float r = 0.03597789207798663f; // ln(10000)/256
    int c = blockIdx.x;
    int t = threadIdx.x;
    int i = c >> 3;
    int j = ((c & 7) << 6) | t;
    float ph;
    if (j < 256) ph = sinf((float)i * expf(-(float)j * r));
    else         ph = cosf((float)i * expf(-(float)(j - 256) * r));
    PH[c * 64 + t] = ph;
    int tt = c >> 1;
    float dv = expf(-(float)tt * r);
    PW[c * 64 + t] = (c & 1) ? cosf((float)t * dv) : sinf((float)t * dv);
}

// ---------------------------------------------------------------- weights -> bf16
__global__ __launch_bounds__(256) void wconv_kernel(
    const float* __restrict__ wq, const float* __restrict__ wk,
    const float* __restrict__ wv, const float* __restrict__ wo,
    u16* __restrict__ WT, u16* __restrict__ WOb) {
    int i = blockIdx.x * 256 + threadIdx.x;   // [0, 131072)
    if (i < 98304) {
        float v;
        if (i < 32768)      v = wq[i];
        else if (i < 65536) v = wk[i - 32768];
        else                v = wv[i - 65536];
        WT[i] = f2bf(v);
    } else {
        WOb[i - 98304] = f2bf(wo[i - 98304]);
    }
}

// ---------------------------------------------------------------- x+pos -> XT bf16 [b][p][c]
__global__ __launch_bounds__(256) void xpose_kernel(
    const float* __restrict__ x, const float* __restrict__ PH,
    const float* __restrict__ PW, u16* __restrict__ XT) {
    __shared__ u16 T[64 * 68];
    int ct = blockIdx.x;  // c tile [0,8)
    int pt = blockIdx.y;  // h row  [0,64)
    int b  = blockIdx.z;
    int tid = threadIdx.x;
    int c0 = ct * 64;
    const size_t xb = ((size_t)b * 512 + c0) * 4096 + pt * 64;
#pragma unroll
    for (int it = 0; it < 16; ++it) {
        int idx = tid + it * 256;
        int cl = idx >> 6, pl = idx & 63;
        float v = x[xb + (size_t)cl * 4096 + pl]
                + PH[(c0 + cl) * 64 + pt] + PW[(c0 + cl) * 64 + pl];
        T[pl * 68 + cl] = f2bf(v);
    }
    __syncthreads();
#pragma unroll
    for (int jt = 0; jt < 4; ++jt) {
        int row = jt * 16 + (tid >> 4);
        int cq  = tid & 15;
        ushort4 val = *(const ushort4*)&T[row * 68 + cq * 4];
        *(ushort4*)&XT[((size_t)b * 4096 + pt * 64 + row) * 512 + c0 + cq * 4] = val;
    }
}

// ---------------------------------------------------------------- qkv GEMM via MFMA
// XOR-swizzled LDS: slot (r, s) holds global k-chunk (s ^ (r&7))
__global__ __launch_bounds__(256) void qkvm_kernel(
    const u16* __restrict__ XT, const u16* __restrict__ WT,
    const float* __restrict__ bq, const float* __restrict__ bk,
    const float* __restrict__ bv,
    u16* __restrict__ QHt, u16* __restrict__ QWt,
    u16* __restrict__ KHt, u16* __restrict__ KWt,
    u16* __restrict__ VHt, u16* __restrict__ Vb) {
    __shared__ u16 Ab[64 * 64];    //  8 KB  [m][c]
    __shared__ u16 Bb[256 * 64];   // 32 KB  [p][c]
    int pt = blockIdx.x;   // [0,16)
    int mg = blockIdx.y;   // [0,3)  q/k/v
    int b  = blockIdx.z;
    int tid  = threadIdx.x;
    int w    = tid >> 6;
    int lane = tid & 63;
    int ln15 = lane & 15, quad = lane >> 4;
    int p0 = pt * 256;
    const u16* Wg = WT + mg * 64 * 512;
    const u16* Xg = XT + ((size_t)b * 4096 + p0) * 512;

    f32x4 acc[4][4];
#pragma unroll
    for (int mf = 0; mf < 4; ++mf)
#pragma unroll
        for (int pf = 0; pf < 4; ++pf)
            acc[mf][pf] = (f32x4){0.f, 0.f, 0.f, 0.f};

    for (int kc = 0; kc < 512; kc += 64) {
        __syncthreads();
#pragma unroll
        for (int it = 0; it < 2; ++it) {
            int idx = tid + it * 256;
            int r = idx >> 3, s = idx & 7;
            gll16(Wg + r * 512 + kc + ((s ^ (r & 7)) * 8), &Ab[idx * 8]);
        }
#pragma unroll
        for (int it = 0; it < 8; ++it) {
            int idx = tid + it * 256;
            int r = idx >> 3, s = idx & 7;
            gll16(Xg + (size_t)r * 512 + kc + ((s ^ (r & 7)) * 8), &Bb[idx * 8]);
        }
        __syncthreads();
#pragma unroll
        for (int ks = 0; ks < 2; ++ks) {
            int cs = ks * 4 + quad;
            short8 af[4], bf[4];
#pragma unroll
            for (int mf = 0; mf < 4; ++mf) {
                int row = mf * 16 + ln15;
                af[mf] = *(const short8*)&Ab[row * 64 + ((cs ^ (row & 7)) * 8)];
            }
#pragma unroll
            for (int pf = 0; pf < 4; ++pf) {
                int row = w * 64 + pf * 16 + ln15;
                bf[pf] = *(const short8*)&Bb[row * 64 + ((cs ^ (row & 7)) * 8)];
            }
#pragma unroll
            for (int mf = 0; mf < 4; ++mf)
#pragma unroll
                for (int pf = 0; pf < 4; ++pf)
                    acc[mf][pf] = __builtin_amdgcn_mfma_f32_16x16x32_bf16(
                        af[mf], bf[pf], acc[mf][pf], 0, 0, 0);
        }
    }

    const float* bias = (mg == 0) ? bq : (mg == 1) ? bk : bv;
    if (mg == 2) {
#pragma unroll
        for (int mf = 0; mf < 4; ++mf)
#pragma unroll
            for (int pf = 0; pf < 4; ++pf) {
                int p = p0 + w * 64 + pf * 16 + ln15;
                int h = p >> 6, wc = p & 63;
#pragma unroll
                for (int reg = 0; reg < 4; ++reg) {
                    int hc = quad * 4 + reg;
                    int m  = mf * 16 + hc;
                    u16 bfv = f2bf(acc[mf][pf][reg] + bias[m]);
                    VHt[(((b * 4 + mf) * 64 + wc) * 16 + hc) * 64 + h] = bfv;
                    Vb[((size_t)(b * 64 + m)) * 4096 + p] = bfv;
                }
            }
    } else {
        u16* Ht = (mg == 1) ? KHt : QHt;
        u16* Wt = (mg == 1) ? KWt : QWt;
#pragma unroll
        for (int mf = 0; mf < 4; ++mf)
#pragma unroll
            for (int pf = 0; pf < 4; ++pf) {
                int p = p0 + w * 64 + pf * 16 + ln15;
                int h = p >> 6, wc = p & 63;
                ushort4 pk;
                pk.x = f2bf(acc[mf][pf][0] + bias[mf * 16 + quad * 4 + 0]);
                pk.y = f2bf(acc[mf][pf][1] + bias[mf * 16 + quad * 4 + 1]);
                pk.z = f2bf(acc[mf][pf][2] + bias[mf * 16 + quad * 4 + 2]);
                pk.w = f2bf(acc[mf][pf][3] + bias[mf * 16 + quad * 4 + 3]);
                *(ushort4*)&Ht[(((b * 4 + mf) * 64 + wc) * 64 + h) * 16 + quad * 4] = pk;
                *(ushort4*)&Wt[(((b * 4 + mf) * 64 + h) * 64 + wc) * 16 + quad * 4] = pk;
            }
    }
}

// ---------------------------------------------------------------- fused attention (MFMA)
__global__ __launch_bounds__(256, 4) void attn_kernel(
    const u16* __restrict__ QHt, const u16* __restrict__ QWt,
    const u16* __restrict__ KHt, const u16* __restrict__ KWt,
    const u16* __restrict__ VHt, const u16* __restrict__ Vb,
    float* __restrict__ OH, float* __restrict__ OW) {
    __shared__ u16 A_lds[64 * 40];
    __shared__ u16 B_lds[128 * 40];
    __shared__ u16 VH_lds[16 * 72];
    __shared__ u16 VW_lds[16 * 72];
    __shared__ u16 P_lds[64 * 144];

    int a = blockIdx.x, n = blockIdx.y, b = blockIdx.z;
    int tid  = threadIdx.x;
    int w    = tid >> 6;
    int lane = tid & 63;
    int ln15 = lane & 15, quad = lane >> 4;
    int nv = a >> 4;
    int hv = ((a & 15) << 2) | n;

    const int cb = ((b * 4 + n) * 64 + a) << 10;
    const u16* vb = Vb + ((size_t)(b * 64 + nv * 16)) * 4096 + hv * 64;

    {
        int t = tid & 127;
        const short8 z8 = {0, 0, 0, 0, 0, 0, 0, 0};
        if (tid < 128) {
            short8 vA = *(const short8*)(QHt + cb + t * 8);
            *(short8*)&A_lds[(t >> 1) * 40 + (t & 1) * 8] = vA;
            short8 vK = *(const short8*)(KHt + cb + t * 8);
            *(short8*)&B_lds[(t >> 1) * 40 + (t & 1) * 8] = vK;
            *(short8*)&B_lds[(t >> 1) * 40 + 16 + (t & 1) * 8] = z8;
            short8 vV = *(const short8*)(VHt + cb + t * 8);
            *(short8*)&VH_lds[(t >> 3) * 72 + (t & 7) * 8] = vV;
        } else {
            short8 vA = *(const short8*)(QWt + cb + t * 8);
            *(short8*)&A_lds[(t >> 1) * 40 + 16 + (t & 1) * 8] = vA;
            short8 vK = *(const short8*)(KWt + cb + t * 8);
            *(short8*)&B_lds[(64 + (t >> 1)) * 40 + 16 + (t & 1) * 8] = vK;
            *(short8*)&B_lds[(64 + (t >> 1)) * 40 + (t & 1) * 8] = z8;
            short8 vV = *(const short8*)(vb + (t >> 3) * 4096 + (t & 7) * 8);
            *(short8*)&VW_lds[(t >> 3) * 72 + (t & 7) * 8] = vV;
        }
    }
    __syncthreads();

    const f32x4 zf = {0.f, 0.f, 0.f, 0.f};
    short8 af = *(const short8*)&A_lds[(w * 16 + ln15) * 40 + quad * 8];
    f32x4 acc[8];
#pragma unroll
    for (int nt = 0; nt < 8; ++nt) {
        short8 bf = *(const short8*)&B_lds[(nt * 16 + ln15) * 40 + quad * 8];
        acc[nt] = __builtin_amdgcn_mfma_f32_16x16x32_bf16(af, bf, zf, 0, 0, 0);
    }

#pragma unroll
    for (int nt = 0; nt < 4; ++nt)
#pragma unroll
        for (int r = 0; r < 4; ++r)
            if (nt * 16 + ln15 == w * 16 + quad * 4 + r) acc[nt][r] = -1e30f;

    float inv[4];
#pragma unroll
    for (int r = 0; r < 4; ++r) {
        float mrow = acc[0][r];
#pragma unroll
        for (int nt = 1; nt < 8; ++nt) mrow = fmaxf(mrow, acc[nt][r]);
        mrow = fmaxf(mrow, __shfl_xor(mrow, 1, 64));
        mrow = fmaxf(mrow, __shfl_xor(mrow, 2, 64));
        mrow = fmaxf(mrow, __shfl_xor(mrow, 4, 64));
        mrow = fmaxf(mrow, __shfl_xor(mrow, 8, 64));
        float s = 0.f;
#pragma unroll
        for (int nt = 0; nt < 8; ++nt) {
            float e = __expf(acc[nt][r] - mrow);
            acc[nt][r] = e;
            s += e;
        }
        s += __shfl_xor(s, 1, 64);
        s += __shfl_xor(s, 2, 64);
        s += __shfl_xor(s, 4, 64);
        s += __shfl_xor(s, 8, 64);
        inv[r] = 1.0f / s;
    }
#pragma unroll
    for (int nt = 0; nt < 8; ++nt)
#pragma unroll
        for (int r = 0; r < 4; ++r)
            P_lds[(w * 16 + quad * 4 + r) * 144 + nt * 16 + ln15] =
                f2bf(acc[nt][r] * inv[r]);
    __syncthreads();

    int prow = (w * 16 + ln15) * 144;
    short8 a0 = *(const short8*)&P_lds[prow +       quad * 8];
    short8 a1 = *(const short8*)&P_lds[prow + 32  + quad * 8];
    short8 a2 = *(const short8*)&P_lds[prow + 64  + quad * 8];
    short8 a3 = *(const short8*)&P_lds[prow + 96  + quad * 8];
    short8 b0 = *(const short8*)&VH_lds[ln15 * 72 +      quad * 8];
    short8 b1 = *(const short8*)&VH_lds[ln15 * 72 + 32 + quad * 8];
    short8 c0 = *(const short8*)&VW_lds[ln15 * 72 +      quad * 8];
    short8 c1 = *(const short8*)&VW_lds[ln15 * 72 + 32 + quad * 8];
    f32x4 oH = __builtin_amdgcn_mfma_f32_16x16x32_bf16(a0, b0, zf, 0, 0, 0);
    oH = __builtin_amdgcn_mfma_f32_16x16x32_bf16(a1, b1, oH, 0, 0, 0);
    f32x4 oW = __builtin_amdgcn_mfma_f32_16x16x32_bf16(a2, c0, zf, 0, 0, 0);
    oW = __builtin_amdgcn_mfma_f32_16x16x32_bf16(a3, c1, oW, 0, 0, 0);

#pragma unroll
    for (int r = 0; r < 4; ++r) {
        int dl = quad * 4 + r;
        OH[((b * 64 + ln15 * 4 + w) * 64 + dl * 4 + n) * 64 + a] = oH[r];
        OW[((b * 64 + ln15 * 4 + nv) * 64 + w * 16 + dl) * 64 + hv] = oW[r];
    }
}

// ---------------------------------------------------------------- OH+OW -> Sb bf16 [b][p][c]
__global__ __launch_bounds__(256) void sconv_kernel(
    const float* __restrict__ OH, const float* __restrict__ OW,
    u16* __restrict__ Sb) {
    __shared__ u16 T[64 * 68];
    int pt = blockIdx.x;  // h row [0,64)
    int b  = blockIdx.y;
    int tid = threadIdx.x;
#pragma unroll
    for (int it = 0; it < 16; ++it) {
        int idx = tid + it * 256;
        int cl = idx >> 6, pl = idx & 63;
        int o = (b * 64 + cl) * 4096 + pt * 64 + pl;
        T[pl * 68 + cl] = f2bf(OH[o] + OW[o]);
    }
    __syncthreads();
#pragma unroll
    for (int jt = 0; jt < 4; ++jt) {
        int row = jt * 16 + (tid >> 4);
        int cq  = tid & 15;
        ushort4 val = *(const ushort4*)&T[row * 68 + cq * 4];
        *(ushort4*)&Sb[((size_t)b * 4096 + pt * 64 + row) * 64 + cq * 4] = val;
    }
}

// ---------------------------------------------------------------- final conv via MFMA
// Operand-swapped: A = Sb (p rows) so D rows = p (reg-consecutive -> float4
// epilogue), cols = m. XOR-swizzled LDS chunks kill bank conflicts.
__global__ __launch_bounds__(256) void finalm_kernel(
    const u16* __restrict__ Sb, const u16* __restrict__ WOb,
    const float* __restrict__ bo, const float* __restrict__ gamma,
    const float* __restrict__ x, const float* __restrict__ PH,
    const float* __restrict__ PW, float* __restrict__ out) {
    __shared__ u16 Ab[64 * 64];    //  8 KB  WOb rows [m][c]
    __shared__ u16 Bb[256 * 64];   // 32 KB  Sb  rows [p][c]
    int pt = blockIdx.x;   // [0,16)
    int mc = blockIdx.y;   // [0,8)
    int b  = blockIdx.z;
    int tid  = threadIdx.x;
    int w    = tid >> 6;
    int lane = tid & 63;
    int ln15 = lane & 15, quad = lane >> 4;
    int p0 = pt * 256, m0 = mc * 64;
    const u16* Ag = WOb + m0 * 64;
    const u16* Sg = Sb + ((size_t)b * 4096 + p0) * 64;

#pragma unroll
    for (int it = 0; it < 2; ++it) {
        int idx = tid + it * 256;
        int r = idx >> 3, s = idx & 7;
        gll16(Ag + r * 64 + ((s ^ (r & 7)) * 8), &Ab[idx * 8]);
    }
#pragma unroll
    for (int it = 0; it < 8; ++it) {
        int idx = tid + it * 256;
        int r = idx >> 3, s = idx & 7;
        gll16(Sg + r * 64 + ((s ^ (r & 7)) * 8), &Bb[idx * 8]);
    }
    __syncthreads();

    const f32x4 zf = {0.f, 0.f, 0.f, 0.f};
    f32x4 acc[4][4];
#pragma unroll
    for (int mf = 0; mf < 4; ++mf)
#pragma unroll
        for (int pf = 0; pf < 4; ++pf)
            acc[mf][pf] = zf;
#pragma unroll
    for (int ks = 0; ks < 2; ++ks) {
        int cs = ks * 4 + quad;
        short8 af[4], bf[4];
#pragma unroll
        for (int pf = 0; pf < 4; ++pf) {
            int row = w * 64 + pf * 16 + ln15;
            af[pf] = *(const short8*)&Bb[row * 64 + ((cs ^ (row & 7)) * 8)];
        }
#pragma unroll
        for (int mf = 0; mf < 4; ++mf) {
            int row = mf * 16 + ln15;
            bf[mf] = *(const short8*)&Ab[row * 64 + ((cs ^ (row & 7)) * 8)];
        }
#pragma unroll
        for (int mf = 0; mf < 4; ++mf)
#pragma unroll
            for (int pf = 0; pf < 4; ++pf)
                acc[mf][pf] = __builtin_amdgcn_mfma_f32_16x16x32_bf16(
                    af[pf], bf[mf], acc[mf][pf], 0, 0, 0);
    }

    float g = gamma[0];
    int h = pt * 4 + w;   // p >> 6, wave-uniform
#pragma unroll
    for (int mf = 0; mf < 4; ++mf) {
        int m = m0 + mf * 16 + ln15;
        float bm = bo[m];
        float ph = PH[m * 64 + h];
#pragma unroll
        for (int pf = 0; pf < 4; ++pf) {
            int pb = p0 + w * 64 + pf * 16 + quad * 4;   // 4 consecutive p
            size_t o = ((size_t)(b * 512 + m)) * 4096 + pb;
            float4 xv  = *(const float4*)&x[o];
            float4 pwv = *(const float4*)&PW[m * 64 + pf * 16 + quad * 4];
            float4 res;
            res.x = g * (acc[mf][pf][0] + bm) + xv.x + ph + pwv.x;
            res.y = g * (acc[mf][pf][1] + bm) + xv.y + ph + pwv.y;
            res.z = g * (acc[mf][pf][2] + bm) + xv.z + ph + pwv.z;
            res.w = g * (acc[mf][pf][3] + bm) + xv.w + ph + pwv.w;
            *(float4*)&out[o] = res;
        }
    }
}

// ---------------------------------------------------------------- launch
extern "C" void kernel_launch(void* const* d_in, const int* in_sizes, int n_in,
                              void* d_out, int out_size, void* d_ws, size_t ws_size,
                              hipStream_t stream) {
    const float* x     = (const float*)d_in[0];
    const float* wq    = (const float*)d_in[1];
    const float* bq    = (const float*)d_in[2];
    const float* wk    = (const float*)d_in[3];
    const float* bk    = (const float*)d_in[4];
    const float* wv    = (const float*)d_in[5];
    const float* bv    = (const float*)d_in[6];
    const float* wo    = (const float*)d_in[7];
    const float* bo    = (const float*)d_in[8];
    const float* gamma = (const float*)d_in[9];
    float* out = (float*)d_out;
    float* ws  = (float*)d_ws;

    float* PH = ws;                           // 32768 f32
    float* PW = PH + 32768;                   // 32768 f32
    u16*   WT  = (u16*)(PW + 32768);          // 98304
    u16*   WOb = WT + 98304;                  // 32768
    u16*   XT  = WOb + 32768;                 // 16777216 (33.5 MB)
    u16*   QHt = XT + 16777216;               // 2097152 each (4.2 MB)
    u16*   QWt = QHt + 2097152;
    u16*   KHt = QWt + 2097152;
    u16*   KWt = KHt + 2097152;
    u16*   VHt = KWt + 2097152;
    u16*   Vb  = VHt + 2097152;
    // aliases into XT region (XT dead after qkvm): OH|OW|Sb
    float* OH  = (float*)XT;
    float* OW  = OH + 2097152;
    u16*   Sbb = (u16*)(OW + 2097152);
    // total ws ~ 59.3 MB

    pos_kernel<<<dim3(512), dim3(64), 0, stream>>>(PH, PW);
    wconv_kernel<<<dim3(512), dim3(256), 0, stream>>>(wq, wk, wv, wo, WT, WOb);
    xpose_kernel<<<dim3(8, 64, 8), dim3(256), 0, stream>>>(x, PH, PW, XT);
    qkvm_kernel<<<dim3(16, 3, 8), dim3(256), 0, stream>>>(
        XT, WT, bq, bk, bv, QHt, QWt, KHt, KWt, VHt, Vb);
    attn_kernel<<<dim3(64, 4, 8), dim3(256), 0, stream>>>(
        QHt, QWt, KHt, KWt, VHt, Vb, OH, OW);
    sconv_kernel<<<dim3(64, 8), dim3(256), 0, stream>>>(OH, OW, Sbb);
    finalm_kernel<<<dim3(16, 8, 8), dim3(256), 0, stream>>>(
        Sbb, WOb, bo, gamma, x, PH, PW, out);
}